// Round 22
// baseline (576.608 us; speedup 1.0000x reference)
//
#include <hip/hip_runtime.h>

typedef __attribute__((ext_vector_type(8))) short bfrag;
typedef __attribute__((ext_vector_type(4))) float f4acc;

__device__ inline unsigned short f2bf(float x) {
    unsigned u = __float_as_uint(x);
    unsigned r = (u + 0x7FFF + ((u >> 16) & 1)) >> 16;
    return (unsigned short)r;
}
__device__ inline unsigned short f2bf_t(float x) {   // truncate (positive vals)
    return (unsigned short)(__float_as_uint(x) >> 16);
}
__device__ inline float bf2f(unsigned short h) {
    unsigned u = ((unsigned)h) << 16;
    return __uint_as_float(u);
}

// ---- ALL weight prep in one launch (range-dispatched blocks) ---------------
__global__ __launch_bounds__(256) void prep_all(
    const float* __restrict__ cw, const float* __restrict__ gamma,
    const float* __restrict__ beta, const float* __restrict__ mean,
    const float* __restrict__ var, const float* __restrict__ cb,
    const float* __restrict__ ktw, const float* __restrict__ vtw,
    const float* __restrict__ kqw, const float* __restrict__ vqw,
    unsigned short* __restrict__ W1s, unsigned short* __restrict__ W2bf,
    float* __restrict__ biasP,
    unsigned short* __restrict__ wpkt, unsigned short* __restrict__ wpvt,
    unsigned short* __restrict__ wpkq, unsigned short* __restrict__ wpvq)
{
    const int bid = blockIdx.x;
    const int tid = threadIdx.x;
    if (bid < 256) {
        int ci = bid, co = tid;
        W1s[(ci >> 5) * 8192 + co * 32 + (ci & 31)] = f2bf(cw[co*512 + ci]);
        for (int l = 0; l < 5; ++l) {
            float g = gamma[l*256 + ci];
            float rs = rsqrtf(var[l*256 + ci] + 1e-5f);
            W2bf[l*65536 + co*256 + ci] = f2bf(cw[co*512 + 256 + ci] * g * rs);
        }
    } else if (bid < 261) {
        int item = (bid - 256) * 256 + tid;
        int l = item >> 8, co = item & 255;
        float acc = cb[co];
        for (int ci = 0; ci < 256; ++ci) {
            float g = gamma[l*256+ci];
            float rs = rsqrtf(var[l*256+ci] + 1e-5f);
            float k = beta[l*256+ci] - g*rs*mean[l*256+ci];
            acc += cw[co*512 + 256 + ci] * k;
        }
        biasP[l*256 + co] = acc;
    } else if (bid < 549) {
        int g = (bid - 261) * 256 + tid;
        int ic = g & 255; int rest = g >> 8; int oc = rest % 32; int tap = rest / 32;
        wpkt[g] = f2bf(ktw[((size_t)oc * 256 + ic) * 9 + tap]);
    } else if (bid < 1701) {
        int g = (bid - 549) * 256 + tid;
        int ic = g & 255; int rest = g >> 8; int oc = rest % 128; int tap = rest / 128;
        wpvt[g] = f2bf(vtw[((size_t)oc * 256 + ic) * 9 + tap]);
    } else if (bid < 3141) {
        int gt = (bid - 1701) * 256 + tid;
        int lev = gt / 73728; int g = gt - lev * 73728;
        int ic = g & 255; int rest = g >> 8; int oc = rest % 32; int tap = rest / 32;
        wpkq[(size_t)lev * 73728 + g] = f2bf(kqw[(size_t)lev * 73728 + ((size_t)oc * 256 + ic) * 9 + tap]);
    } else {
        int gt = (bid - 3141) * 256 + tid;
        int lev = gt / 294912; int g = gt - lev * 294912;
        int ic = g & 255; int rest = g >> 8; int oc = rest % 128; int tap = rest / 128;
        wpvq[(size_t)lev * 294912 + g] = f2bf(vqw[(size_t)lev * 294912 + ((size_t)oc * 256 + ic) * 9 + tap]);
    }
}

// -------- merged conv3x3 implicit GEMM: path0 (att imgs 0..14) + path1 (fr5) -
template<int OC>
__global__ __launch_bounds__(256) void convgemm2(
    const float* __restrict__ in0, const unsigned short* __restrict__ Wp0,
    const float* __restrict__ b0, void* __restrict__ out0, float s0, int mode0,
    const float* __restrict__ in1, const unsigned short* __restrict__ Wp1,
    int w1_lstride, const float* __restrict__ b1, int b1_lstride,
    void* __restrict__ out1, float s1, int mode1)
{
    __shared__ unsigned short ldsB[64 * 72];   // [px][ic_local], stride 72 u16
    const int t = threadIdx.x;
    const int gimg = blockIdx.y;
    const int p0 = blockIdx.x * 64;
    const int lane = t & 63, w = t >> 6, l15 = lane & 15, g = lane >> 4;
    constexpr int MF = (OC == 128) ? 4 : 2;
    constexpr int NF = (OC == 128) ? 2 : 1;
    constexpr int WN = (OC == 128) ? 2 : 4;
    const int wm = w / WN, wn = w % WN;
    const int oc0w = wm * MF * 16;
    const int px0w = wn * NF * 16;

    const float* inb; const unsigned short* Wb; const float* bb;
    void* outp; float scale; int mode; int img;
    if (gimg < 15) {
        img = gimg; inb = in0 + (size_t)gimg * 262144;
        Wb = Wp0; bb = b0; outp = out0; scale = s0; mode = mode0;
    } else {
        int zi = gimg - 15; int lev = zi >> 1;
        img = zi; inb = in1 + (size_t)zi * 262144;
        Wb = Wp1 + (size_t)lev * w1_lstride; bb = b1 + lev * b1_lstride;
        outp = out1; scale = s1; mode = mode1;
    }

    const int px_l = t & 63;
    const int icg = t >> 6;
    const int pxg = p0 + px_l;
    const int y = pxg >> 5, x = pxg & 31;

    f4acc acc[MF][NF];
    #pragma unroll
    for (int m = 0; m < MF; ++m)
        #pragma unroll
        for (int n = 0; n < NF; ++n) acc[m][n] = (f4acc){0.f, 0.f, 0.f, 0.f};

    for (int tap = 0; tap < 9; ++tap) {
        const int dy = tap / 3 - 1, dx = tap % 3 - 1;
        const int sy = y + dy, sx = x + dx;
        const bool ok = ((unsigned)sy < 32u) && ((unsigned)sx < 32u);
        const int soff = ok ? (sy * 32 + sx) : 0;
        const unsigned short* Wtap = Wb + (size_t)tap * OC * 256;
        for (int ics = 0; ics < 4; ++ics) {
            const int ic0 = ics * 64;
            __syncthreads();
            {
                const float* src = inb + (size_t)(ic0 + icg * 16) * 1024 + soff;
                unsigned uu[8];
                #pragma unroll
                for (int e = 0; e < 8; ++e) {
                    float v0 = src[(size_t)(2 * e) * 1024];
                    float v1 = src[(size_t)(2 * e + 1) * 1024];
                    v0 = ok ? v0 : 0.f;
                    v1 = ok ? v1 : 0.f;
                    uu[e] = (unsigned)f2bf(v0) | ((unsigned)f2bf(v1) << 16);
                }
                *((uint4*)&ldsB[px_l * 72 + icg * 16])     = make_uint4(uu[0], uu[1], uu[2], uu[3]);
                *((uint4*)&ldsB[px_l * 72 + icg * 16 + 8]) = make_uint4(uu[4], uu[5], uu[6], uu[7]);
            }
            __syncthreads();
            #pragma unroll
            for (int ks = 0; ks < 2; ++ks) {
                const int kc = ic0 + ks * 32;
                bfrag a[MF], bf[NF];
                #pragma unroll
                for (int m = 0; m < MF; ++m)
                    a[m] = *((const bfrag*)(Wtap + (size_t)(oc0w + m * 16 + l15) * 256 + kc + g * 8));
                #pragma unroll
                for (int n = 0; n < NF; ++n)
                    bf[n] = *((const bfrag*)&ldsB[(px0w + n * 16 + l15) * 72 + ks * 32 + g * 8]);
                #pragma unroll
                for (int m = 0; m < MF; ++m)
                    #pragma unroll
                    for (int n = 0; n < NF; ++n)
                        acc[m][n] = __builtin_amdgcn_mfma_f32_16x16x32_bf16(a[m], bf[n], acc[m][n], 0, 0, 0);
            }
        }
    }
    #pragma unroll
    for (int m = 0; m < MF; ++m) {
        #pragma unroll
        for (int n = 0; n < NF; ++n) {
            const int px = p0 + px0w + n * 16 + l15;
            #pragma unroll
            for (int j = 0; j < 4; ++j) {
                const int oc = oc0w + m * 16 + g * 4 + j;
                float val = acc[m][n][j] + bb[oc];
                if (mode == 1)
                    ((unsigned short*)outp)[((size_t)img * 1024 + px) * OC + oc] = f2bf(val * scale);
                else if (mode == 2) {
                    int chunk = ((oc >> 4) << 5) + (px >> 5);
                    int lidx = (oc & 15) | (((px >> 3) & 3) << 4);
                    ((unsigned short*)outp)[(size_t)img * 131072 + ((size_t)chunk << 9) + lidx * 8 + (px & 7)] = f2bf(val);
                } else {
                    ((unsigned short*)outp)[((size_t)img * 1024 + px) * 256 + oc] = f2bf(val * scale);
                }
            }
        }
    }
}

// ------ bilinear resize, all levels in one launch: f(H,W) -> fr5[lev](32,32) -
struct ResArgs { const float* f[5]; int H[5], W[5]; };

__global__ __launch_bounds__(256) void resize_all(
    ResArgs A, float* __restrict__ fr5)
{
    const int lev = blockIdx.y;
    const int H = A.H[lev], W = A.W[lev];
    int g = blockIdx.x * 256 + threadIdx.x;
    int s = g & 1023;
    int c = (g >> 10) & 255;
    int b = g >> 18;
    int oy = s >> 5, ox = s & 31;
    float ty = (float)(oy * (H-1)) / 31.0f;
    float tx = (float)(ox * (W-1)) / 31.0f;
    int y0 = (int)ty; float wy = ty - y0;
    int y1 = min(y0+1, H-1);
    int x0 = (int)tx; float wx = tx - x0;
    int x1 = min(x0+1, W-1);
    const float* p = A.f[lev] + ((size_t)b*256 + c) * (size_t)(H*W);
    float v00 = p[y0*W+x0], v01 = p[y0*W+x1];
    float v10 = p[y1*W+x0], v11 = p[y1*W+x1];
    fr5[(size_t)lev * 524288 + g] = (v00*(1.f-wx) + v01*wx)*(1.f-wy) + (v10*(1.f-wx) + v11*wx)*wy;
}

// ---------------- MFMA flash attention, 1-wave blocks, 2 s-subtiles ---------
__global__ __launch_bounds__(64) void attn_mfma(
    const unsigned short* __restrict__ kqT16,  // [10][1024][32]
    const unsigned short* __restrict__ ktT16,  // [15][1024][32] (x log2e)
    const unsigned short* __restrict__ vt16,   // [15] frag-order chunks
    unsigned short* __restrict__ part)         // [15][10][128][1024] bf16
{
    __shared__ unsigned short P[32 * 136];
    __shared__ float sums[32];
    const int lane = threadIdx.x;
    const int l15 = lane & 15;
    const int g = lane >> 4;
    const int s0 = blockIdx.x * 32;
    const int n = blockIdx.y, z = blockIdx.z;

    const bfrag qa0 = *(const bfrag*)(ktT16 + ((size_t)n*1024 + s0 + l15)*32 + g*8);
    const bfrag qa1 = *(const bfrag*)(ktT16 + ((size_t)n*1024 + s0 + 16 + l15)*32 + g*8);

    f4acc oacc0[8], oacc1[8];
    #pragma unroll
    for (int ct = 0; ct < 8; ++ct) {
        oacc0[ct] = (f4acc){0.f,0.f,0.f,0.f};
        oacc1[ct] = (f4acc){0.f,0.f,0.f,0.f};
    }
    float rs0[4] = {0.f,0.f,0.f,0.f}, rs1[4] = {0.f,0.f,0.f,0.f};

    const unsigned short* Kbase = kqT16 + (size_t)z * 32768;
    const unsigned short* Vbase = vt16 + (size_t)n * 131072;

    for (int mt = 0; mt < 8; ++mt) {
        const int m0 = mt * 128;
        #pragma unroll
        for (int j = 0; j < 8; ++j) {
            bfrag kb = *(const bfrag*)(Kbase + (size_t)(m0 + j*16 + l15)*32 + g*8);
            f4acc sf0 = __builtin_amdgcn_mfma_f32_16x16x32_bf16(qa0, kb, (f4acc){0.f,0.f,0.f,0.f}, 0, 0, 0);
            f4acc sf1 = __builtin_amdgcn_mfma_f32_16x16x32_bf16(qa1, kb, (f4acc){0.f,0.f,0.f,0.f}, 0, 0, 0);
            #pragma unroll
            for (int r = 0; r < 4; ++r) {
                float e0 = __builtin_amdgcn_exp2f(sf0[r]); rs0[r] += e0;
                P[(g*4 + r)*136 + j*16 + l15] = f2bf_t(e0);
                float e1 = __builtin_amdgcn_exp2f(sf1[r]); rs1[r] += e1;
                P[(16 + g*4 + r)*136 + j*16 + l15] = f2bf_t(e1);
            }
        }
        __builtin_amdgcn_s_setprio(1);
        #pragma unroll
        for (int ks = 0; ks < 4; ++ks) {
            bfrag pb0 = *(const bfrag*)(P + l15*136 + ks*32 + g*8);
            bfrag pb1 = *(const bfrag*)(P + (16 + l15)*136 + ks*32 + g*8);
            #pragma unroll
            for (int ct = 0; ct < 8; ++ct) {
                bfrag va = *(const bfrag*)(Vbase + (((size_t)(ct*32 + mt*4 + ks)) << 9) + lane*8);
                oacc0[ct] = __builtin_amdgcn_mfma_f32_16x16x32_bf16(va, pb0, oacc0[ct], 0, 0, 0);
                oacc1[ct] = __builtin_amdgcn_mfma_f32_16x16x32_bf16(va, pb1, oacc1[ct], 0, 0, 0);
            }
        }
        __builtin_amdgcn_s_setprio(0);
    }
    #pragma unroll
    for (int d = 1; d < 16; d <<= 1)
        #pragma unroll
        for (int r = 0; r < 4; ++r) {
            rs0[r] += __shfl_xor(rs0[r], d, 64);
            rs1[r] += __shfl_xor(rs1[r], d, 64);
        }
    if (l15 == 0) {
        #pragma unroll
        for (int r = 0; r < 4; ++r) {
            sums[g*4 + r] = rs0[r];
            sums[16 + g*4 + r] = rs1[r];
        }
    }
    float inv0 = 1.f / sums[l15];
    float inv1 = 1.f / sums[16 + l15];
    unsigned short* pb0 = part + (((size_t)n*10 + z)*128)*1024 + s0 + l15;
    #pragma unroll
    for (int ct = 0; ct < 8; ++ct)
        #pragma unroll
        for (int r = 0; r < 4; ++r) {
            pb0[(size_t)(ct*16 + g*4 + r)*1024]      = f2bf(oacc0[ct][r] * inv0);
            pb0[(size_t)(ct*16 + g*4 + r)*1024 + 16] = f2bf(oacc1[ct][r] * inv1);
        }
}

// -------- fin16T[z][s][128+c] = sum_n part[n][z][c][s]  (transposing reduce) -
__global__ __launch_bounds__(256) void reduce_part_t(
    const unsigned short* __restrict__ part, unsigned short* __restrict__ fin16T)
{
    __shared__ float tile[32][33];
    const int s0b = blockIdx.x * 32;
    const int c0b = blockIdx.y * 32;
    const int z   = blockIdx.z;
    const int tx = threadIdx.x & 31;
    const int ty = threadIdx.x >> 5;
    #pragma unroll
    for (int i = 0; i < 4; ++i) {
        int c = c0b + ty + i*8;
        float acc = 0.f;
        #pragma unroll
        for (int n = 0; n < 15; ++n)
            acc += bf2f(part[(((size_t)n*10 + z)*128 + c)*1024 + s0b + tx]);
        tile[ty + i*8][tx] = acc;
    }
    __syncthreads();
    #pragma unroll
    for (int i = 0; i < 4; ++i) {
        int s = s0b + ty + i*8;
        fin16T[((size_t)z*1024 + s)*256 + 128 + c0b + tx] = f2bf(tile[tx][ty + i*8]);
    }
}

// ---------------- G = W2' * fin + bias' : register-only bf16 MFMA GEMM ------
__global__ __launch_bounds__(256) void g_mfma(
    const unsigned short* __restrict__ fin16T,  // [10][1024][256]
    const unsigned short* __restrict__ W2bf,    // [5][256][256]
    const float* __restrict__ biasP,            // [5][256]
    float* __restrict__ G5)                     // [10][256][1024]
{
    const int t = threadIdx.x;
    const int lane = t & 63, w = t >> 6, l15 = lane & 15, g = lane >> 4;
    const int p0 = blockIdx.x * 64;
    const int zb = blockIdx.y;
    const int lev = zb >> 1;
    const int co0 = w * 64;
    f4acc acc[4][4];
    #pragma unroll
    for (int m = 0; m < 4; ++m)
        #pragma unroll
        for (int n = 0; n < 4; ++n) acc[m][n] = (f4acc){0.f,0.f,0.f,0.f};
    const unsigned short* A = W2bf + (size_t)lev * 65536;
    const unsigned short* B = fin16T + (size_t)zb * 262144;
    for (int kc = 0; kc < 256; kc += 32) {
        bfrag a[4], b[4];
        #pragma unroll
        for (int m = 0; m < 4; ++m)
            a[m] = *((const bfrag*)(A + (size_t)(co0 + m*16 + l15)*256 + kc + g*8));
        #pragma unroll
        for (int n = 0; n < 4; ++n)
            b[n] = *((const bfrag*)(B + (size_t)(p0 + n*16 + l15)*256 + kc + g*8));
        #pragma unroll
        for (int m = 0; m < 4; ++m)
            #pragma unroll
            for (int n = 0; n < 4; ++n)
                acc[m][n] = __builtin_amdgcn_mfma_f32_16x16x32_bf16(a[m], b[n], acc[m][n], 0, 0, 0);
    }
    #pragma unroll
    for (int m = 0; m < 4; ++m)
        #pragma unroll
        for (int n = 0; n < 4; ++n) {
            int px = p0 + n*16 + l15;
            #pragma unroll
            for (int j = 0; j < 4; ++j) {
                int co = co0 + m*16 + g*4 + j;
                G5[(size_t)zb*262144 + (size_t)co*1024 + px] = acc[m][n][j] + biasP[lev*256 + co];
            }
        }
}

// ---- out = W1*f + bilerp(G): fused levels, LDS-free, px-split 32px/block ---
// Block: 256 co x 32 px. acc[4][2] (32 VGPR) -> high occupancy; f not
// duplicated (px partitioned); duplicated G reads are L2/L3-resident.
struct OutArgs {
    const float* f[5];
    int H[5], W[5];
    int tileOff[6];
    long long ooff[5];
};

__global__ __launch_bounds__(256) void out_mfma(
    OutArgs A, const unsigned short* __restrict__ W1s,
    const float* __restrict__ G5, float* __restrict__ outp)
{
    const int bid = blockIdx.x;
    int l = 0;
    #pragma unroll
    for (int i = 1; i < 5; ++i) if (bid >= A.tileOff[i]) l = i;
    const int H = A.H[l], W = A.W[l], HW = H * W;
    const int p0 = (bid - A.tileOff[l]) * 32;
    const int b = blockIdx.y;
    const int t = threadIdx.x;
    const int lane = t & 63;
    const int wid = t >> 6;
    const int cw0 = wid * 64;
    const int l15 = lane & 15;
    const int g = lane >> 4;
    const int pxb = p0 + l15 * 2;
    const bool al2 = ((HW & 1) == 0);

    // ---- preload bilerp(G) into accumulator (C-in); acc[m][n][j] <-> px=pxb+n
    const float* G = G5 + (size_t)(l * 2 + b) * 262144;
    f4acc acc[4][2];
    #pragma unroll
    for (int n = 0; n < 2; ++n) {
        int px = pxb + n;
        int pc = (px < HW) ? px : 0;
        int yy = pc / W;
        int xx = pc - yy * W;
        float ty = (float)(yy * 31) / (float)(H - 1);
        float tx = (float)(xx * 31) / (float)(W - 1);
        int y0 = (int)ty; float wy = ty - y0;
        int x0 = (int)tx; float wx = tx - x0;
        int y1 = min(y0 + 1, 31), x1 = min(x0 + 1, 31);
        float w00 = (1.f-wy)*(1.f-wx), w01 = (1.f-wy)*wx;
        float w10 = wy*(1.f-wx),       w11 = wy*wx;
        int i00 = y0*32+x0, i01 = y0*32+x1, i10 = y1*32+x0, i11 = y1*32+x1;
        #pragma unroll
        for (int m = 0; m < 4; ++m) {
            #pragma unroll
            for (int j = 0; j < 4; ++j) {
                int co = cw0 + m*16 + g*4 + j;
                const float* gb = G + (size_t)co * 1024;
                acc[m][n][j] = gb[i00]*w00 + gb[i01]*w01 + gb[i10]*w10 + gb[i11]*w11;
            }
        }
    }

    const float* fb = A.f[l] + (size_t)b * 256 * HW;
    const bool fullv = al2 && (pxb + 1 < HW);

    for (int s = 0; s < 8; ++s) {
        bfrag a[4], bb[2];
        #pragma unroll
        for (int m = 0; m < 4; ++m)
            a[m] = *((const bfrag*)(W1s + (size_t)s * 8192 + (cw0 + m*16 + l15) * 32 + g * 8));
        const float* src = fb + (size_t)(s * 32 + g * 8) * HW;
        if (fullv) {
            #pragma unroll
            for (int e = 0; e < 8; ++e) {
                float2 v = *((const float2*)(src + (size_t)e * HW + pxb));
                bb[0][e] = (short)f2bf(v.x);
                bb[1][e] = (short)f2bf(v.y);
            }
        } else {
            #pragma unroll
            for (int e = 0; e < 8; ++e) {
                #pragma unroll
                for (int q = 0; q < 2; ++q) {
                    int px = pxb + q;
                    float v = (px < HW) ? src[(size_t)e * HW + px] : 0.f;
                    bb[q][e] = (short)f2bf(v);
                }
            }
        }
        #pragma unroll
        for (int m = 0; m < 4; ++m)
            #pragma unroll
            for (int n = 0; n < 2; ++n)
                acc[m][n] = __builtin_amdgcn_mfma_f32_16x16x32_bf16(a[m], bb[n], acc[m][n], 0, 0, 0);
    }

    // ---- epilogue: float2 coalesced stores ----
    float* op = outp + A.ooff[l] + (size_t)b * 256 * HW;
    if (fullv) {
        #pragma unroll
        for (int m = 0; m < 4; ++m) {
            #pragma unroll
            for (int j = 0; j < 4; ++j) {
                int co = cw0 + m*16 + g*4 + j;
                float2 v = make_float2(acc[m][0][j], acc[m][1][j]);
                *((float2*)(op + (size_t)co * HW + pxb)) = v;
            }
        }
    } else {
        #pragma unroll
        for (int m = 0; m < 4; ++m) {
            #pragma unroll
            for (int j = 0; j < 4; ++j) {
                int co = cw0 + m*16 + g*4 + j;
                #pragma unroll
                for (int q = 0; q < 2; ++q) {
                    int px = pxb + q;
                    if (px < HW) op[(size_t)co * HW + px] = acc[m][q][j];
                }
            }
        }
    }
}

extern "C" void kernel_launch(void* const* d_in, const int* in_sizes, int n_in,
                              void* d_out, int out_size, void* d_ws, size_t ws_size,
                              hipStream_t stream)
{
    const float* f[5]; for (int i = 0; i < 5; ++i) f[i] = (const float*)d_in[i];
    const float* att   = (const float*)d_in[5];
    const float* ktw   = (const float*)d_in[6];
    const float* ktb   = (const float*)d_in[7];
    const float* vtw   = (const float*)d_in[8];
    const float* vtb   = (const float*)d_in[9];
    const float* kqw   = (const float*)d_in[10];
    const float* kqbb  = (const float*)d_in[11];
    const float* vqw   = (const float*)d_in[12];
    const float* vqb   = (const float*)d_in[13];
    const float* gamma = (const float*)d_in[14];
    const float* beta  = (const float*)d_in[15];
    const float* mean  = (const float*)d_in[16];
    const float* var   = (const float*)d_in[17];
    const float* cw    = (const float*)d_in[18];
    const float* cb    = (const float*)d_in[19];
    float* outp = (float*)d_out;

    unsigned short* ktT16 = (unsigned short*)d_ws;      // 491520 u16
    unsigned short* kqT16 = ktT16 + 491520;             // 327680
    unsigned short* vt16  = kqT16 + 327680;             // 1966080
    unsigned short* wpkt  = vt16 + 1966080;             // 73728
    unsigned short* wpvt  = wpkt + 73728;               // 294912
    unsigned short* wpkq  = wpvt + 294912;              // 368640
    unsigned short* wpvq  = wpkq + 368640;              // 1474560
    unsigned short* W1s   = wpvq + 1474560;             // 65536
    unsigned short* W2bf  = W1s + 65536;                // 327680
    unsigned short* fin16T= W2bf + 327680;              // 2621440
    unsigned short* partb = fin16T + 2621440;           // 19660800
    float* biasP = (float*)(partb + 19660800);          // 1280 f
    float* fr5   = biasP + 1280;                        // 2621440 f
    float* G5    = fr5 + 2621440;                       // 2621440 f

    prep_all<<<8901, 256, 0, stream>>>(cw, gamma, beta, mean, var, cb,
                                       ktw, vtw, kqw, vqw,
                                       W1s, W2bf, biasP, wpkt, wpvt, wpkq, wpvq);

    const int Hs[5] = {200,100,50,25,13};
    const int Ws[5] = {336,168,84,42,21};
    ResArgs ra;
    for (int l = 0; l < 5; ++l) { ra.f[l] = f[l]; ra.H[l] = Hs[l]; ra.W[l] = Ws[l]; }
    resize_all<<<dim3(2048, 5), 256, 0, stream>>>(ra, fr5);

    convgemm2<32><<<dim3(16, 25), 256, 0, stream>>>(
        att, wpkt, ktb, ktT16, 1.4426950408889634f, 1,
        fr5, wpkq, 73728, kqbb, 32, kqT16, 1.f, 1);
    convgemm2<128><<<dim3(16, 25), 256, 0, stream>>>(
        att, wpvt, vtb, vt16, 1.f, 2,
        fr5, wpvq, 294912, vqb, 128, fin16T, 15.f, 3);

    attn_mfma<<<dim3(32, 15, 10), 64, 0, stream>>>(kqT16, ktT16, vt16, partb);
    reduce_part_t<<<dim3(32, 4, 10), 256, 0, stream>>>(partb, fin16T);
    g_mfma<<<dim3(16, 10), 256, 0, stream>>>(fin16T, W2bf, biasP, G5);

    OutArgs oa;
    int toff = 0;
    long long ooff = 0;
    for (int l = 0; l < 5; ++l) {
        oa.f[l] = f[l]; oa.H[l] = Hs[l]; oa.W[l] = Ws[l];
        oa.tileOff[l] = toff;
        oa.ooff[l] = ooff;
        int HW = Hs[l] * Ws[l];
        toff += (HW + 31) / 32;
        ooff += (long long)2 * 256 * HW;
    }
    oa.tileOff[5] = toff;
    out_mfma<<<dim3(toff, 2), 256, 0, stream>>>(oa, W1s, G5, outp);
}

// Round 23
// 534.094 us; speedup vs baseline: 1.0796x; 1.0796x over previous
//
#include <hip/hip_runtime.h>

typedef __attribute__((ext_vector_type(8))) short bfrag;
typedef __attribute__((ext_vector_type(4))) float f4acc;

__device__ inline unsigned short f2bf(float x) {
    unsigned u = __float_as_uint(x);
    unsigned r = (u + 0x7FFF + ((u >> 16) & 1)) >> 16;
    return (unsigned short)r;
}
__device__ inline float bf2f(unsigned short h) {
    unsigned u = ((unsigned)h) << 16;
    return __uint_as_float(u);
}

// ---- ALL weight prep in one launch (range-dispatched blocks) ---------------
__global__ __launch_bounds__(256) void prep_all(
    const float* __restrict__ cw, const float* __restrict__ gamma,
    const float* __restrict__ beta, const float* __restrict__ mean,
    const float* __restrict__ var, const float* __restrict__ cb,
    const float* __restrict__ ktw, const float* __restrict__ vtw,
    const float* __restrict__ kqw, const float* __restrict__ vqw,
    unsigned short* __restrict__ W1s, unsigned short* __restrict__ W2bf,
    float* __restrict__ biasP,
    unsigned short* __restrict__ wpkt, unsigned short* __restrict__ wpvt,
    unsigned short* __restrict__ wpkq, unsigned short* __restrict__ wpvq)
{
    const int bid = blockIdx.x;
    const int tid = threadIdx.x;
    if (bid < 256) {
        int ci = bid, co = tid;
        W1s[(ci >> 5) * 8192 + co * 32 + (ci & 31)] = f2bf(cw[co*512 + ci]);
        for (int l = 0; l < 5; ++l) {
            float g = gamma[l*256 + ci];
            float rs = rsqrtf(var[l*256 + ci] + 1e-5f);
            W2bf[l*65536 + co*256 + ci] = f2bf(cw[co*512 + 256 + ci] * g * rs);
        }
    } else if (bid < 261) {
        int item = (bid - 256) * 256 + tid;
        int l = item >> 8, co = item & 255;
        float acc = cb[co];
        for (int ci = 0; ci < 256; ++ci) {
            float g = gamma[l*256+ci];
            float rs = rsqrtf(var[l*256+ci] + 1e-5f);
            float k = beta[l*256+ci] - g*rs*mean[l*256+ci];
            acc += cw[co*512 + 256 + ci] * k;
        }
        biasP[l*256 + co] = acc;
    } else if (bid < 549) {
        int g = (bid - 261) * 256 + tid;
        int ic = g & 255; int rest = g >> 8; int oc = rest % 32; int tap = rest / 32;
        wpkt[g] = f2bf(ktw[((size_t)oc * 256 + ic) * 9 + tap]);
    } else if (bid < 1701) {
        int g = (bid - 549) * 256 + tid;
        int ic = g & 255; int rest = g >> 8; int oc = rest % 128; int tap = rest / 128;
        wpvt[g] = f2bf(vtw[((size_t)oc * 256 + ic) * 9 + tap]);
    } else if (bid < 3141) {
        int gt = (bid - 1701) * 256 + tid;
        int lev = gt / 73728; int g = gt - lev * 73728;
        int ic = g & 255; int rest = g >> 8; int oc = rest % 32; int tap = rest / 32;
        wpkq[(size_t)lev * 73728 + g] = f2bf(kqw[(size_t)lev * 73728 + ((size_t)oc * 256 + ic) * 9 + tap]);
    } else {
        int gt = (bid - 3141) * 256 + tid;
        int lev = gt / 294912; int g = gt - lev * 294912;
        int ic = g & 255; int rest = g >> 8; int oc = rest % 128; int tap = rest / 128;
        wpvq[(size_t)lev * 294912 + g] = f2bf(vqw[(size_t)lev * 294912 + ((size_t)oc * 256 + ic) * 9 + tap]);
    }
}

// -------- merged conv3x3 implicit GEMM: path0 (att imgs 0..14) + path1 (fr5) -
template<int OC>
__global__ __launch_bounds__(256) void convgemm2(
    const float* __restrict__ in0, const unsigned short* __restrict__ Wp0,
    const float* __restrict__ b0, void* __restrict__ out0, float s0, int mode0,
    const float* __restrict__ in1, const unsigned short* __restrict__ Wp1,
    int w1_lstride, const float* __restrict__ b1, int b1_lstride,
    void* __restrict__ out1, float s1, int mode1)
{
    __shared__ unsigned short ldsB[64 * 72];   // [px][ic_local], stride 72 u16
    const int t = threadIdx.x;
    const int gimg = blockIdx.y;
    const int p0 = blockIdx.x * 64;
    const int lane = t & 63, w = t >> 6, l15 = lane & 15, g = lane >> 4;
    constexpr int MF = (OC == 128) ? 4 : 2;
    constexpr int NF = (OC == 128) ? 2 : 1;
    constexpr int WN = (OC == 128) ? 2 : 4;
    const int wm = w / WN, wn = w % WN;
    const int oc0w = wm * MF * 16;
    const int px0w = wn * NF * 16;

    const float* inb; const unsigned short* Wb; const float* bb;
    void* outp; float scale; int mode; int img;
    if (gimg < 15) {
        img = gimg; inb = in0 + (size_t)gimg * 262144;
        Wb = Wp0; bb = b0; outp = out0; scale = s0; mode = mode0;
    } else {
        int zi = gimg - 15; int lev = zi >> 1;
        img = zi; inb = in1 + (size_t)zi * 262144;
        Wb = Wp1 + (size_t)lev * w1_lstride; bb = b1 + lev * b1_lstride;
        outp = out1; scale = s1; mode = mode1;
    }

    const int px_l = t & 63;
    const int icg = t >> 6;
    const int pxg = p0 + px_l;
    const int y = pxg >> 5, x = pxg & 31;

    f4acc acc[MF][NF];
    #pragma unroll
    for (int m = 0; m < MF; ++m)
        #pragma unroll
        for (int n = 0; n < NF; ++n) acc[m][n] = (f4acc){0.f, 0.f, 0.f, 0.f};

    for (int tap = 0; tap < 9; ++tap) {
        const int dy = tap / 3 - 1, dx = tap % 3 - 1;
        const int sy = y + dy, sx = x + dx;
        const bool ok = ((unsigned)sy < 32u) && ((unsigned)sx < 32u);
        const int soff = ok ? (sy * 32 + sx) : 0;
        const unsigned short* Wtap = Wb + (size_t)tap * OC * 256;
        for (int ics = 0; ics < 4; ++ics) {
            const int ic0 = ics * 64;
            __syncthreads();
            {
                const float* src = inb + (size_t)(ic0 + icg * 16) * 1024 + soff;
                unsigned uu[8];
                #pragma unroll
                for (int e = 0; e < 8; ++e) {
                    float v0 = src[(size_t)(2 * e) * 1024];
                    float v1 = src[(size_t)(2 * e + 1) * 1024];
                    v0 = ok ? v0 : 0.f;
                    v1 = ok ? v1 : 0.f;
                    uu[e] = (unsigned)f2bf(v0) | ((unsigned)f2bf(v1) << 16);
                }
                *((uint4*)&ldsB[px_l * 72 + icg * 16])     = make_uint4(uu[0], uu[1], uu[2], uu[3]);
                *((uint4*)&ldsB[px_l * 72 + icg * 16 + 8]) = make_uint4(uu[4], uu[5], uu[6], uu[7]);
            }
            __syncthreads();
            #pragma unroll
            for (int ks = 0; ks < 2; ++ks) {
                const int kc = ic0 + ks * 32;
                bfrag a[MF], bf[NF];
                #pragma unroll
                for (int m = 0; m < MF; ++m)
                    a[m] = *((const bfrag*)(Wtap + (size_t)(oc0w + m * 16 + l15) * 256 + kc + g * 8));
                #pragma unroll
                for (int n = 0; n < NF; ++n)
                    bf[n] = *((const bfrag*)&ldsB[(px0w + n * 16 + l15) * 72 + ks * 32 + g * 8]);
                #pragma unroll
                for (int m = 0; m < MF; ++m)
                    #pragma unroll
                    for (int n = 0; n < NF; ++n)
                        acc[m][n] = __builtin_amdgcn_mfma_f32_16x16x32_bf16(a[m], bf[n], acc[m][n], 0, 0, 0);
            }
        }
    }
    #pragma unroll
    for (int m = 0; m < MF; ++m) {
        #pragma unroll
        for (int n = 0; n < NF; ++n) {
            const int px = p0 + px0w + n * 16 + l15;
            #pragma unroll
            for (int j = 0; j < 4; ++j) {
                const int oc = oc0w + m * 16 + g * 4 + j;
                float val = acc[m][n][j] + bb[oc];
                if (mode == 1)
                    ((unsigned short*)outp)[((size_t)img * 1024 + px) * OC + oc] = f2bf(val * scale);
                else if (mode == 2) {
                    int chunk = ((oc >> 4) << 5) + (px >> 5);
                    int lidx = (oc & 15) | (((px >> 3) & 3) << 4);
                    ((unsigned short*)outp)[(size_t)img * 131072 + ((size_t)chunk << 9) + lidx * 8 + (px & 7)] = f2bf(val);
                } else {
                    ((unsigned short*)outp)[((size_t)img * 1024 + px) * 256 + oc] = f2bf(val * scale);
                }
            }
        }
    }
}

// ------ bilinear resize, all levels in one launch: f(H,W) -> fr5[lev](32,32) -
struct ResArgs { const float* f[5]; int H[5], W[5]; };

__global__ __launch_bounds__(256) void resize_all(
    ResArgs A, float* __restrict__ fr5)
{
    const int lev = blockIdx.y;
    const int H = A.H[lev], W = A.W[lev];
    int g = blockIdx.x * 256 + threadIdx.x;
    int s = g & 1023;
    int c = (g >> 10) & 255;
    int b = g >> 18;
    int oy = s >> 5, ox = s & 31;
    float ty = (float)(oy * (H-1)) / 31.0f;
    float tx = (float)(ox * (W-1)) / 31.0f;
    int y0 = (int)ty; float wy = ty - y0;
    int y1 = min(y0+1, H-1);
    int x0 = (int)tx; float wx = tx - x0;
    int x1 = min(x0+1, W-1);
    const float* p = A.f[lev] + ((size_t)b*256 + c) * (size_t)(H*W);
    float v00 = p[y0*W+x0], v01 = p[y0*W+x1];
    float v10 = p[y1*W+x0], v11 = p[y1*W+x1];
    fr5[(size_t)lev * 524288 + g] = (v00*(1.f-wx) + v01*wx)*(1.f-wy) + (v10*(1.f-wx) + v11*wx)*wy;
}

// ---------------- MFMA flash attention, 1-wave blocks, 2 s-subtiles ---------
__global__ __launch_bounds__(64) void attn_mfma(
    const unsigned short* __restrict__ kqT16,  // [10][1024][32]
    const unsigned short* __restrict__ ktT16,  // [15][1024][32] (x log2e)
    const unsigned short* __restrict__ vt16,   // [15] frag-order chunks
    unsigned short* __restrict__ part)         // [15][10][128][1024] bf16
{
    __shared__ unsigned short P[32 * 136];
    __shared__ float sums[32];
    const int lane = threadIdx.x;
    const int l15 = lane & 15;
    const int g = lane >> 4;
    const int s0 = blockIdx.x * 32;
    const int n = blockIdx.y, z = blockIdx.z;

    const bfrag qa0 = *(const bfrag*)(ktT16 + ((size_t)n*1024 + s0 + l15)*32 + g*8);
    const bfrag qa1 = *(const bfrag*)(ktT16 + ((size_t)n*1024 + s0 + 16 + l15)*32 + g*8);

    f4acc oacc0[8], oacc1[8];
    #pragma unroll
    for (int ct = 0; ct < 8; ++ct) {
        oacc0[ct] = (f4acc){0.f,0.f,0.f,0.f};
        oacc1[ct] = (f4acc){0.f,0.f,0.f,0.f};
    }
    float rs0[4] = {0.f,0.f,0.f,0.f}, rs1[4] = {0.f,0.f,0.f,0.f};

    const unsigned short* Kbase = kqT16 + (size_t)z * 32768;
    const unsigned short* Vbase = vt16 + (size_t)n * 131072;

    for (int mt = 0; mt < 8; ++mt) {
        const int m0 = mt * 128;
        #pragma unroll
        for (int j = 0; j < 8; ++j) {
            bfrag kb = *(const bfrag*)(Kbase + (size_t)(m0 + j*16 + l15)*32 + g*8);
            f4acc sf0 = __builtin_amdgcn_mfma_f32_16x16x32_bf16(qa0, kb, (f4acc){0.f,0.f,0.f,0.f}, 0, 0, 0);
            f4acc sf1 = __builtin_amdgcn_mfma_f32_16x16x32_bf16(qa1, kb, (f4acc){0.f,0.f,0.f,0.f}, 0, 0, 0);
            #pragma unroll
            for (int r = 0; r < 4; ++r) {
                float e0 = __builtin_amdgcn_exp2f(sf0[r]); rs0[r] += e0;
                P[(g*4 + r)*136 + j*16 + l15] = f2bf(e0);
                float e1 = __builtin_amdgcn_exp2f(sf1[r]); rs1[r] += e1;
                P[(16 + g*4 + r)*136 + j*16 + l15] = f2bf(e1);
            }
        }
        __builtin_amdgcn_s_setprio(1);
        #pragma unroll
        for (int ks = 0; ks < 4; ++ks) {
            bfrag pb0 = *(const bfrag*)(P + l15*136 + ks*32 + g*8);
            bfrag pb1 = *(const bfrag*)(P + (16 + l15)*136 + ks*32 + g*8);
            #pragma unroll
            for (int ct = 0; ct < 8; ++ct) {
                bfrag va = *(const bfrag*)(Vbase + (((size_t)(ct*32 + mt*4 + ks)) << 9) + lane*8);
                oacc0[ct] = __builtin_amdgcn_mfma_f32_16x16x32_bf16(va, pb0, oacc0[ct], 0, 0, 0);
                oacc1[ct] = __builtin_amdgcn_mfma_f32_16x16x32_bf16(va, pb1, oacc1[ct], 0, 0, 0);
            }
        }
        __builtin_amdgcn_s_setprio(0);
    }
    #pragma unroll
    for (int d = 1; d < 16; d <<= 1)
        #pragma unroll
        for (int r = 0; r < 4; ++r) {
            rs0[r] += __shfl_xor(rs0[r], d, 64);
            rs1[r] += __shfl_xor(rs1[r], d, 64);
        }
    if (l15 == 0) {
        #pragma unroll
        for (int r = 0; r < 4; ++r) {
            sums[g*4 + r] = rs0[r];
            sums[16 + g*4 + r] = rs1[r];
        }
    }
    float inv0 = 1.f / sums[l15];
    float inv1 = 1.f / sums[16 + l15];
    unsigned short* pb0 = part + (((size_t)n*10 + z)*128)*1024 + s0 + l15;
    #pragma unroll
    for (int ct = 0; ct < 8; ++ct)
        #pragma unroll
        for (int r = 0; r < 4; ++r) {
            pb0[(size_t)(ct*16 + g*4 + r)*1024]      = f2bf(oacc0[ct][r] * inv0);
            pb0[(size_t)(ct*16 + g*4 + r)*1024 + 16] = f2bf(oacc1[ct][r] * inv1);
        }
}

// -------- fin16T[z][s][128+c] = sum_n part[n][z][c][s]  (transposing reduce) -
__global__ __launch_bounds__(256) void reduce_part_t(
    const unsigned short* __restrict__ part, unsigned short* __restrict__ fin16T)
{
    __shared__ float tile[32][33];
    const int s0b = blockIdx.x * 32;
    const int c0b = blockIdx.y * 32;
    const int z   = blockIdx.z;
    const int tx = threadIdx.x & 31;
    const int ty = threadIdx.x >> 5;
    #pragma unroll
    for (int i = 0; i < 4; ++i) {
        int c = c0b + ty + i*8;
        float acc = 0.f;
        #pragma unroll
        for (int n = 0; n < 15; ++n)
            acc += bf2f(part[(((size_t)n*10 + z)*128 + c)*1024 + s0b + tx]);
        tile[ty + i*8][tx] = acc;
    }
    __syncthreads();
    #pragma unroll
    for (int i = 0; i < 4; ++i) {
        int s = s0b + ty + i*8;
        fin16T[((size_t)z*1024 + s)*256 + 128 + c0b + tx] = f2bf(tile[tx][ty + i*8]);
    }
}

// ---------------- G = W2' * fin + bias' : register-only bf16 MFMA GEMM ------
__global__ __launch_bounds__(256) void g_mfma(
    const unsigned short* __restrict__ fin16T,  // [10][1024][256]
    const unsigned short* __restrict__ W2bf,    // [5][256][256]
    const float* __restrict__ biasP,            // [5][256]
    float* __restrict__ G5)                     // [10][256][1024]
{
    const int t = threadIdx.x;
    const int lane = t & 63, w = t >> 6, l15 = lane & 15, g = lane >> 4;
    const int p0 = blockIdx.x * 64;
    const int zb = blockIdx.y;
    const int lev = zb >> 1;
    const int co0 = w * 64;
    f4acc acc[4][4];
    #pragma unroll
    for (int m = 0; m < 4; ++m)
        #pragma unroll
        for (int n = 0; n < 4; ++n) acc[m][n] = (f4acc){0.f,0.f,0.f,0.f};
    const unsigned short* A = W2bf + (size_t)lev * 65536;
    const unsigned short* B = fin16T + (size_t)zb * 262144;
    for (int kc = 0; kc < 256; kc += 32) {
        bfrag a[4], b[4];
        #pragma unroll
        for (int m = 0; m < 4; ++m)
            a[m] = *((const bfrag*)(A + (size_t)(co0 + m*16 + l15)*256 + kc + g*8));
        #pragma unroll
        for (int n = 0; n < 4; ++n)
            b[n] = *((const bfrag*)(B + (size_t)(p0 + n*16 + l15)*256 + kc + g*8));
        #pragma unroll
        for (int m = 0; m < 4; ++m)
            #pragma unroll
            for (int n = 0; n < 4; ++n)
                acc[m][n] = __builtin_amdgcn_mfma_f32_16x16x32_bf16(a[m], b[n], acc[m][n], 0, 0, 0);
    }
    #pragma unroll
    for (int m = 0; m < 4; ++m)
        #pragma unroll
        for (int n = 0; n < 4; ++n) {
            int px = p0 + n*16 + l15;
            #pragma unroll
            for (int j = 0; j < 4; ++j) {
                int co = co0 + m*16 + g*4 + j;
                G5[(size_t)zb*262144 + (size_t)co*1024 + px] = acc[m][n][j] + biasP[lev*256 + co];
            }
        }
}

// ---- out = W1*f + bilerp(G): fused levels, LDS-free, float4 I/O ------------
// (empirical optimum: 64 px x 256 co, scalar-G C-in preload, float4 f I/O)
struct OutArgs {
    const float* f[5];
    int H[5], W[5];
    int tileOff[6];
    long long ooff[5];
};

__global__ __launch_bounds__(256) void out_mfma(
    OutArgs A, const unsigned short* __restrict__ W1s,
    const float* __restrict__ G5, float* __restrict__ outp)
{
    const int bid = blockIdx.x;
    int l = 0;
    #pragma unroll
    for (int i = 1; i < 5; ++i) if (bid >= A.tileOff[i]) l = i;
    const int H = A.H[l], W = A.W[l], HW = H * W;
    const int p0 = (bid - A.tileOff[l]) * 64;
    const int b = blockIdx.y;
    const int t = threadIdx.x;
    const int lane = t & 63;
    const int wid = t >> 6;
    const int cw0 = wid * 64;
    const int l15 = lane & 15;
    const int g = lane >> 4;
    const int pxb = p0 + l15 * 4;
    const bool al4 = ((HW & 3) == 0);

    const float* G = G5 + (size_t)(l * 2 + b) * 262144;
    f4acc acc[4][4];
    #pragma unroll
    for (int n = 0; n < 4; ++n) {
        int px = pxb + n;
        int pc = (px < HW) ? px : 0;
        int yy = pc / W;
        int xx = pc - yy * W;
        float ty = (float)(yy * 31) / (float)(H - 1);
        float tx = (float)(xx * 31) / (float)(W - 1);
        int y0 = (int)ty; float wy = ty - y0;
        int x0 = (int)tx; float wx = tx - x0;
        int y1 = min(y0 + 1, 31), x1 = min(x0 + 1, 31);
        float w00 = (1.f-wy)*(1.f-wx), w01 = (1.f-wy)*wx;
        float w10 = wy*(1.f-wx),       w11 = wy*wx;
        int i00 = y0*32+x0, i01 = y0*32+x1, i10 = y1*32+x0, i11 = y1*32+x1;
        #pragma unroll
        for (int m = 0; m < 4; ++m) {
            #pragma unroll
            for (int j = 0; j < 4; ++j) {
                int co = cw0 + m*16 + g*4 + j;
                const float* gb = G + (size_t)co * 1024;
                acc[m][n][j] = gb[i00]*w00 + gb[i01]*w01 + gb[i10]*w10 + gb[i11]*w11;
            }
        }
    }

    const float* fb = A.f[l] + (size_t)b * 256 * HW;
    const bool fullv = al4 && (pxb + 3 < HW);

    for (int s = 0; s < 8; ++s) {
        bfrag a[4], bb[4];
        #pragma unroll
        for (int m = 0; m < 4; ++m)
            a[m] = *((const bfrag*)(W1s + (size_t)s * 8192 + (cw0 + m*16 + l15) * 32 + g * 8));
        const float* src = fb + (size_t)(s * 32 + g * 8) * HW;
        if (fullv) {
            #pragma unroll
            for (int e = 0; e < 8; ++e) {
                float4 v = *((const float4*)(src + (size_t)e * HW + pxb));
                bb[0][e] = (short)f2bf(v.x);
                bb[1][e] = (short)f2bf(v.y);
                bb[2][e] = (short)f2bf(v.z);
                bb[3][e] = (short)f2bf(v.w);
            }
        } else {
            #pragma unroll
            for (int e = 0; e < 8; ++e) {
                #pragma unroll
                for (int q = 0; q < 4; ++q) {
                    int px = pxb + q;
                    float v = (px < HW) ? src[(size_t)e * HW + px] : 0.f;
                    bb[q][e] = (short)f2bf(v);
                }
            }
        }
        #pragma unroll
        for (int m = 0; m < 4; ++m)
            #pragma unroll
            for (int n = 0; n < 4; ++n)
                acc[m][n] = __builtin_amdgcn_mfma_f32_16x16x32_bf16(a[m], bb[n], acc[m][n], 0, 0, 0);
    }

    float* op = outp + A.ooff[l] + (size_t)b * 256 * HW;
    if (fullv) {
        #pragma unroll
        for (int m = 0; m < 4; ++m) {
            #pragma unroll
            for (int j = 0; j < 4; ++j) {
                int co = cw0 + m*16 + g*4 + j;
                float4 v = make_float4(acc[m][0][j], acc[m][1][j], acc[m][2][j], acc[m][3][j]);
                *((float4*)(op + (size_t)co * HW + pxb)) = v;
            }
        }
    } else {
        #pragma unroll
        for (int m = 0; m < 4; ++m) {
            #pragma unroll
            for (int j = 0; j < 4; ++j) {
                int co = cw0 + m*16 + g*4 + j;
                #pragma unroll
                for (int q = 0; q < 4; ++q) {
                    int px = pxb + q;
                    if (px < HW) op[(size_t)co * HW + px] = acc[m][q][j];
                }
            }
        }
    }
}

extern "C" void kernel_launch(void* const* d_in, const int* in_sizes, int n_in,
                              void* d_out, int out_size, void* d_ws, size_t ws_size,
                              hipStream_t stream)
{
    const float* f[5]; for (int i = 0; i < 5; ++i) f[i] = (const float*)d_in[i];
    const float* att   = (const float*)d_in[5];
    const float* ktw   = (const float*)d_in[6];
    const float* ktb   = (const float*)d_in[7];
    const float* vtw   = (const float*)d_in[8];
    const float* vtb   = (const float*)d_in[9];
    const float* kqw   = (const float*)d_in[10];
    const float* kqbb  = (const float*)d_in[11];
    const float* vqw   = (const float*)d_in[12];
    const float* vqb   = (const float*)d_in[13];
    const float* gamma = (const float*)d_in[14];
    const float* beta  = (const float*)d_in[15];
    const float* mean  = (const float*)d_in[16];
    const float* var   = (const float*)d_in[17];
    const float* cw    = (const float*)d_in[18];
    const float* cb    = (const float*)d_in[19];
    float* outp = (float*)d_out;

    unsigned short* ktT16 = (unsigned short*)d_ws;      // 491520 u16
    unsigned short* kqT16 = ktT16 + 491520;             // 327680
    unsigned short* vt16  = kqT16 + 327680;             // 1966080
    unsigned short* wpkt  = vt16 + 1966080;             // 73728
    unsigned short* wpvt  = wpkt + 73728;               // 294912
    unsigned short* wpkq  = wpvt + 294912;              // 368640
    unsigned short* wpvq  = wpkq + 368640;              // 1474560
    unsigned short* W1s   = wpvq + 1474560;             // 65536
    unsigned short* W2bf  = W1s + 65536;                // 327680
    unsigned short* fin16T= W2bf + 327680;              // 2621440
    unsigned short* partb = fin16T + 2621440;           // 19660800
    float* biasP = (float*)(partb + 19660800);          // 1280 f
    float* fr5   = biasP + 1280;                        // 2621440 f
    float* G5    = fr5 + 2621440;                       // 2621440 f

    prep_all<<<8901, 256, 0, stream>>>(cw, gamma, beta, mean, var, cb,
                                       ktw, vtw, kqw, vqw,
                                       W1s, W2bf, biasP, wpkt, wpvt, wpkq, wpvq);

    const int Hs[5] = {200,100,50,25,13};
    const int Ws[5] = {336,168,84,42,21};
    ResArgs ra;
    for (int l = 0; l < 5; ++l) { ra.f[l] = f[l]; ra.H[l] = Hs[l]; ra.W[l] = Ws[l]; }
    resize_all<<<dim3(2048, 5), 256, 0, stream>>>(ra, fr5);

    convgemm2<32><<<dim3(16, 25), 256, 0, stream>>>(
        att, wpkt, ktb, ktT16, 1.4426950408889634f, 1,
        fr5, wpkq, 73728, kqbb, 32, kqT16, 1.f, 1);
    convgemm2<128><<<dim3(16, 25), 256, 0, stream>>>(
        att, wpvt, vtb, vt16, 1.f, 2,
        fr5, wpvq, 294912, vqb, 128, fin16T, 15.f, 3);

    attn_mfma<<<dim3(32, 15, 10), 64, 0, stream>>>(kqT16, ktT16, vt16, partb);
    reduce_part_t<<<dim3(32, 4, 10), 256, 0, stream>>>(partb, fin16T);
    g_mfma<<<dim3(16, 10), 256, 0, stream>>>(fin16T, W2bf, biasP, G5);

    OutArgs oa;
    int toff = 0;
    long long ooff = 0;
    for (int l = 0; l < 5; ++l) {
        oa.f[l] = f[l]; oa.H[l] = Hs[l]; oa.W[l] = Ws[l];
        oa.tileOff[l] = toff;
        oa.ooff[l] = ooff;
        int HW = Hs[l] * Ws[l];
        toff += (HW + 63) / 64;
        ooff += (long long)2 * 256 * HW;
    }
    oa.tileOff[5] = toff;
    out_mfma<<<dim3(toff, 2), 256, 0, stream>>>(oa, W1s, G5, outp);
}